// Round 5
// baseline (355.623 us; speedup 1.0000x reference)
//
#include <hip/hip_runtime.h>
#include <math.h>

#define BN 128
#define DN 1024
#define CN 32768
#define NB 64              // score cols per block (16 per wave)
#define NBLK (CN / NB)     // 512 blocks

typedef float f32x4 __attribute__((ext_vector_type(4)));
typedef short short8 __attribute__((ext_vector_type(8)));

static __device__ inline unsigned short f2b(float f) {
    union { float f; unsigned u; } v; v.f = f;
    unsigned r = v.u + 0x7FFF + ((v.u >> 16) & 1);   // RNE
    return (unsigned short)(r >> 16);
}

// ---------------------------------------------------------------------------
// k0: convert inp (128x1024 fp32) -> bf16 into ws (L2-resident A operand),
//     and zero the loss accumulator. 64 blocks x 256 thr x 8 elems.
// ---------------------------------------------------------------------------
__global__ __launch_bounds__(256)
void k0_cvt(const float* __restrict__ inp, unsigned short* __restrict__ Abf,
            float* __restrict__ out_loss)
{
    const int i = blockIdx.x * 256 + threadIdx.x;
    if (i == 0) out_loss[0] = 0.0f;
    float4 a = *(const float4*)&inp[(size_t)i * 8];
    float4 b = *(const float4*)&inp[(size_t)i * 8 + 4];
    short8 s;
    s[0] = f2b(a.x); s[1] = f2b(a.y); s[2] = f2b(a.z); s[3] = f2b(a.w);
    s[4] = f2b(b.x); s[5] = f2b(b.y); s[6] = f2b(b.z); s[7] = f2b(b.w);
    *(short8*)&Abf[(size_t)i * 8] = s;
}

// ---------------------------------------------------------------------------
// k1: barrier-free streaming scores GEMM + em->out_em copy + per-row stats.
// Each lane streams ONE em row (its wave's col = lane&15), loading its own
// MFMA B-fragment (32B contiguous) directly from global, converting to bf16
// in-register, and storing the fp32 copy to out_em. A-fragments read from
// the L2-resident bf16 copy. No LDS staging, no main-loop barriers.
// acc[m][r] = score[row = m*16 + lq*4 + r][col = c0 + w*16 + lr].
// ---------------------------------------------------------------------------
__global__ __launch_bounds__(256)
void k1_gemm_stats(const float* __restrict__ em,
                   const unsigned short* __restrict__ Abf,
                   float* __restrict__ out_em, float* __restrict__ ws)
{
    __shared__ float4 smp[BN][4];   // per-wave stat partials

    const int t   = threadIdx.x;
    const int blk = blockIdx.x;
    const int w   = t >> 6;
    const int l   = t & 63;
    const int lr  = l & 15, lq = l >> 4;

    const size_t col = (size_t)blk * NB + w * 16 + lr;   // em row this lane streams
    const float4* __restrict__ emp  = (const float4*)&em[col * DN];
    float4* __restrict__       outp = (float4*)&out_em[col * DN];

    f32x4 acc[8];
#pragma unroll
    for (int m = 0; m < 8; ++m) acc[m] = (f32x4)0.0f;

#pragma unroll 2
    for (int kt = 0; kt < DN; kt += 32) {
        const int kv = (kt >> 2) + lq * 2;     // float4 index of this lane's 32B strip
        const float4 b0 = emp[kv];
        const float4 b1 = emp[kv + 1];
        outp[kv]     = b0;                     // fused em -> out_em copy
        outp[kv + 1] = b1;
        short8 bf;
        bf[0] = f2b(b0.x); bf[1] = f2b(b0.y); bf[2] = f2b(b0.z); bf[3] = f2b(b0.w);
        bf[4] = f2b(b1.x); bf[5] = f2b(b1.y); bf[6] = f2b(b1.z); bf[7] = f2b(b1.w);
        const int ko = kt + lq * 8;
#pragma unroll
        for (int m = 0; m < 8; ++m) {
            const short8 af = *(const short8*)&Abf[(size_t)(m * 16 + lr) * DN + ko];
            acc[m] = __builtin_amdgcn_mfma_f32_16x16x32_bf16(af, bf, acc[m], 0, 0, 0);
        }
    }

    // per-row stats over this wave's 16 cols (owned exclusively by this wave)
#pragma unroll
    for (int m = 0; m < 8; ++m) {
#pragma unroll
        for (int r = 0; r < 4; ++r) {
            float s = acc[m][r] * 20.0f;                       // 1/TAU
            float mx = s;
#pragma unroll
            for (int off = 1; off < 16; off <<= 1) mx = fmaxf(mx, __shfl_xor(mx, off));
            float z   = __expf(s - mx);
            float cnt = (s > 20.0f) ? 1.0f : 0.0f;             // LAMBDA0/TAU
            float ss  = (s > 20.0f) ? s : 0.0f;
#pragma unroll
            for (int off = 1; off < 16; off <<= 1) {
                z   += __shfl_xor(z, off);
                cnt += __shfl_xor(cnt, off);
                ss  += __shfl_xor(ss, off);
            }
            if (lr == 0) smp[m * 16 + lq * 4 + r][w] = make_float4(mx, z, cnt, ss);
        }
    }
    __syncthreads();

    // merge 4 wave-partials per row -> ws[row*NBLK + blk]
    if (t < BN) {
        float4 p0 = smp[t][0];
        float M = p0.x, Z = p0.y, CNT = p0.z, SS = p0.w;
#pragma unroll
        for (int q = 1; q < 4; ++q) {
            float4 p = smp[t][q];
            float Mn = fmaxf(M, p.x);
            Z = Z * __expf(M - Mn) + p.y * __expf(p.x - Mn);
            M = Mn; CNT += p.z; SS += p.w;
        }
        ((float4*)ws)[(size_t)t * NBLK + blk] = make_float4(M, Z, CNT, SS);
    }
}

// ---------------------------------------------------------------------------
// k23: fused finalize (blocks 0..127: loss + ks for row bid) and sequential
//      EMA chains (blocks 128..255: chain for first occurrence j = bid-128).
// ---------------------------------------------------------------------------
__global__ __launch_bounds__(256)
void k23(const float* __restrict__ inp, const float* __restrict__ em,
         const int* __restrict__ tgt, const float* __restrict__ ws,
         const void* __restrict__ epoch_p,
         float* __restrict__ d_loss, float* __restrict__ d_ks,
         float* __restrict__ out_em)
{
    __shared__ float red[4][4];
    __shared__ float dred[4];
    __shared__ float nred[4];

    const int bid = blockIdx.x;
    const int t   = threadIdx.x;
    const int wid = t >> 6, lane = t & 63;

    if (bid < BN) {
        // ------- finalize row i -------
        const int i = bid;
        float m = -INFINITY, z = 0.f, cnt = 0.f, ss = 0.f;
        for (int c = t; c < NBLK; c += 256) {
            float4 wv = ((const float4*)ws)[(size_t)i * NBLK + c];
            float M = fmaxf(m, wv.x);
            z = z * __expf(m - M) + wv.y * __expf(wv.x - M);
            m = M; cnt += wv.z; ss += wv.w;
        }
#pragma unroll
        for (int off = 1; off < 64; off <<= 1) {
            float m2 = __shfl_xor(m, off), z2 = __shfl_xor(z, off);
            float M = fmaxf(m, m2);
            z = z * __expf(m - M) + z2 * __expf(m2 - M);
            m = M;
            cnt += __shfl_xor(cnt, off);
            ss  += __shfl_xor(ss, off);
        }
        if (lane == 0) { red[wid][0] = m; red[wid][1] = z; red[wid][2] = cnt; red[wid][3] = ss; }

        const int y = tgt[i];
        float4 a = *(const float4*)&inp[(size_t)i * DN + t * 4];
        float4 b = *(const float4*)&em[(size_t)y * DN + t * 4];
        float d = a.x * b.x + a.y * b.y + a.z * b.z + a.w * b.w;
#pragma unroll
        for (int off = 1; off < 64; off <<= 1) d += __shfl_xor(d, off);
        if (lane == 0) dred[wid] = d;
        __syncthreads();

        if (t == 0) {
            float M = red[0][0], Z = red[0][1], CNT = red[0][2], SS = red[0][3];
#pragma unroll
            for (int q = 1; q < 4; ++q) {
                float m2 = red[q][0], z2 = red[q][1];
                float Mn = fmaxf(M, m2);
                Z = Z * __expf(M - Mn) + z2 * __expf(m2 - Mn);
                M = Mn; CNT += red[q][2]; SS += red[q][3];
            }
            float sy  = (dred[0] + dred[1] + dred[2] + dred[3]) * 20.0f;
            float lse = M + logf(Z);
            float A   = SS - CNT * lse;
            float ki  = (CNT > 1.0f) ? (1.0f / (CNT * logf(CNT))) : 0.0f;
            float sum_t = ki * (A - ((sy > 20.0f) ? (sy - lse) : 0.0f)) + (sy - lse);
            atomicAdd(d_loss, -sum_t * (1.0f / 128.0f));
            d_ks[i] = CNT;
        }
        return;
    }

    // ------- EMA chain for j -------
    const int j = bid - BN;
    const int y = tgt[j];
    for (int p = 0; p < j; ++p)
        if (tgt[p] == y) return;   // not first occurrence (block-uniform)

    int ei = *(const int*)epoch_p;
    float e = (ei >= 0 && ei < 1000000) ? (float)ei : *(const float*)epoch_p;
    const float mu = fminf(0.4f / 60.0f * (e + 1.0f), 1.0f);
    const float om = 1.0f - mu;

    float4 r = *(const float4*)&em[(size_t)y * DN + t * 4];   // original em row
    for (int p = j; p < BN; ++p) {
        if (tgt[p] != y) continue;
        float4 x = *(const float4*)&inp[(size_t)p * DN + t * 4];
        r.x = mu * r.x + om * x.x;
        r.y = mu * r.y + om * x.y;
        r.z = mu * r.z + om * x.z;
        r.w = mu * r.w + om * x.w;
        float n = r.x * r.x + r.y * r.y + r.z * r.z + r.w * r.w;
#pragma unroll
        for (int off = 1; off < 64; off <<= 1) n += __shfl_xor(n, off);
        if (lane == 0) nred[wid] = n;
        __syncthreads();
        n = nred[0] + nred[1] + nred[2] + nred[3];
        float inv = 1.0f / sqrtf(n);
        r.x *= inv; r.y *= inv; r.z *= inv; r.w *= inv;
        __syncthreads();
    }
    *(float4*)&out_em[(size_t)y * DN + t * 4] = r;
}

extern "C" void kernel_launch(void* const* d_in, const int* in_sizes, int n_in,
                              void* d_out, int out_size, void* d_ws, size_t ws_size,
                              hipStream_t stream)
{
    const float* inp = (const float*)d_in[0];
    const float* em  = (const float*)d_in[1];
    const int*   tgt = (const int*)d_in[2];
    const void*  ep  = d_in[3];

    float* loss   = (float*)d_out;       // [1]
    float* ks     = loss + 1;            // [128]
    float* out_em = ks + BN;             // [32768*1024]

    float* ws = (float*)d_ws;                            // [128][512] float4 = 1 MB
    unsigned short* Abf = (unsigned short*)(ws + (size_t)BN * NBLK * 4);  // 256 KB bf16 A

    k0_cvt<<<BN * DN / (256 * 8), 256, 0, stream>>>(inp, Abf, loss);
    k1_gemm_stats<<<NBLK, 256, 0, stream>>>(em, Abf, out_em, ws);
    k23<<<2 * BN, 256, 0, stream>>>(inp, em, tgt, ws, ep, loss, ks, out_em);
}